// Round 1
// 957.345 us; speedup vs baseline: 1.0409x; 1.0409x over previous
//
#include <hip/hip_runtime.h>
#include <hip/hip_bf16.h>

#define NN 100000
#define NE 3200000
#define NF 512
#define NH 256
#define NL 64
#define NB_SCAN 391   // ceil(NN/256)
#define PAD 40        // LDS row stride in bf16 elems

#define NBKT 64       // dst-range buckets for scatter locality
#define NPB 1563      // ceil(NN/NBKT) nodes per bucket
#define CPB 32        // chunk-blocks per bucket in k_scatter2

typedef __bf16 bf16x8 __attribute__((ext_vector_type(8)));
typedef __bf16 bf16x4 __attribute__((ext_vector_type(4)));
typedef __bf16 bf16x2 __attribute__((ext_vector_type(2)));
typedef float  f32x4  __attribute__((ext_vector_type(4)));

// ---------------- CSR build ----------------
// Histogram + per-edge within-row rank (the atomic's return value IS the rank).
__global__ void k_hist_rank(const int* __restrict__ dst, int* __restrict__ deg,
                            int* __restrict__ rank) {
    int e = blockIdx.x * 256 + threadIdx.x;
    if (e < NE) {
        int r = atomicAdd(&deg[dst[e]], 1);
        rank[e] = r;
    }
}

__global__ void k_blocksum(const int* __restrict__ deg, int* __restrict__ bsum) {
    __shared__ int s[256];
    int t = threadIdx.x;
    int i = blockIdx.x * 256 + t;
    s[t] = (i < NN) ? deg[i] : 0;
    __syncthreads();
    for (int off = 128; off > 0; off >>= 1) {
        if (t < off) s[t] += s[t + off];
        __syncthreads();
    }
    if (t == 0) bsum[blockIdx.x] = s[0];
}

__global__ void k_scan_partials(int* bsum) {
    __shared__ int s[512];
    int t = threadIdx.x;
    int v = (t < NB_SCAN) ? bsum[t] : 0;
    s[t] = v;
    __syncthreads();
    for (int off = 1; off < 512; off <<= 1) {
        int a = (t >= off) ? s[t - off] : 0;
        __syncthreads();
        s[t] += a;
        __syncthreads();
    }
    if (t < NB_SCAN) bsum[t] = s[t] - v;  // exclusive
}

__global__ void k_scan_final(const int* __restrict__ deg, const int* __restrict__ boff,
                             int* __restrict__ row_ptr) {
    __shared__ int s[2][256];
    int t = threadIdx.x;
    int i = blockIdx.x * 256 + t;
    int v = (i < NN) ? deg[i] : 0;
    int buf = 0;
    s[0][t] = v;
    __syncthreads();
    for (int off = 1; off < 256; off <<= 1) {
        int nv = s[buf][t] + ((t >= off) ? s[buf][t - off] : 0);
        buf ^= 1;
        s[buf][t] = nv;
        __syncthreads();
    }
    if (i < NN) row_ptr[i] = boff[blockIdx.x] + s[buf][t] - v;  // exclusive
}

// Bucket bases: staging layout is congruent with final CSR layout, so
// bucket base = row_ptr[first node of bucket].
__global__ void k_binit(const int* __restrict__ row_ptr, int* __restrict__ bstart,
                        int* __restrict__ bcur) {
    int t = threadIdx.x;
    if (t <= NBKT) {
        long ns = (long)t * NPB;
        int v = (ns >= NN) ? NE : row_ptr[ns];
        bstart[t] = v;
        if (t < NBKT) bcur[t] = v;
    }
}

// Phase 1: partition edges into 64 dst-range buckets. Per-block LDS counting,
// one global reservation atomic per (block,bucket). Final position p is
// precomputed here (row_ptr + rank), no atomics needed downstream.
__global__ __launch_bounds__(256) void k_bucket(const int* __restrict__ src,
                                                const int* __restrict__ dst,
                                                const int* __restrict__ wbits,
                                                const int* __restrict__ rank,
                                                const int* __restrict__ row_ptr,
                                                int* __restrict__ bcur,
                                                int2* __restrict__ stage_sw,
                                                int* __restrict__ stage_p) {
    __shared__ int cnt[NBKT];
    __shared__ int base[NBKT];
    int tid = threadIdx.x;
    if (tid < NBKT) cnt[tid] = 0;
    __syncthreads();
    int e0 = blockIdx.x * 1024;   // NE % 1024 == 0, no bounds check
    int ss[4], ww[4], pp[4], lr[4], bb[4];
#pragma unroll
    for (int k = 0; k < 4; k++) {
        int e = e0 + k * 256 + tid;
        int d = dst[e];
        ss[k] = src[e];
        ww[k] = wbits[e];
        pp[k] = row_ptr[d] + rank[e];
        bb[k] = (int)((unsigned)d / NPB);
        lr[k] = atomicAdd(&cnt[bb[k]], 1);
    }
    __syncthreads();
    if (tid < NBKT) base[tid] = atomicAdd(&bcur[tid], cnt[tid]);
    __syncthreads();
#pragma unroll
    for (int k = 0; k < 4; k++) {
        int pos = base[bb[k]] + lr[k];
        stage_sw[pos] = make_int2(ss[k], ww[k]);
        stage_p[pos] = pp[k];
    }
}

// Phase 2: bucket-major scatter. bucket = blockIdx % 64 -> with round-robin
// block->XCD dispatch, each XCD owns 8 buckets => write working set ~3.2 MB
// fits its 4 MiB L2, so 64B lines fill fully before eviction.
__global__ __launch_bounds__(256) void k_scatter2(const int2* __restrict__ stage_sw,
                                                  const int* __restrict__ stage_p,
                                                  const int* __restrict__ bstart,
                                                  int2* __restrict__ sedge) {
    int b = blockIdx.x & (NBKT - 1);
    int chunk = blockIdx.x >> 6;
    int bs = bstart[b], be = bstart[b + 1];
    for (int i = bs + chunk * 256 + threadIdx.x; i < be; i += CPB * 256)
        sedge[stage_p[i]] = stage_sw[i];
}

// ---------------- weight packing into MFMA B-fragment order ----------------
__global__ void k_packW1(const float* __restrict__ W, __bf16* __restrict__ P) {
    int i = blockIdx.x * 256 + threadIdx.x;       // 131072 = 16nt * 16kc * 64 * 8
    int j = i & 7, l = (i >> 3) & 63, kc = (i >> 9) & 15, nt = i >> 13;
    int k = kc * 32 + (l >> 4) * 8 + j;
    int n = nt * 16 + (l & 15);
    P[i] = (__bf16)W[k * NH + n];
}

__global__ void k_packW2(const float* __restrict__ Wmu, const float* __restrict__ Wlv,
                         __bf16* __restrict__ P) {
    int i = blockIdx.x * 256 + threadIdx.x;       // 32768 = 8nt * 8kc * 64 * 8
    int j = i & 7, l = (i >> 3) & 63, kc = (i >> 9) & 7, nt = i >> 12;
    int k = kc * 32 + (l >> 4) * 8 + j;
    int n = nt * 16 + (l & 15);
    float v = (n < NL) ? Wmu[k * NL + n] : Wlv[k * NL + (n - NL)];
    P[i] = (__bf16)v;
}

// ---------------- GEMM1 (MFMA): XW split into two column-half tables ----------------
// BM=64, BN=256, BK=32. wave wv -> cols [wv*64, wv*64+64); wv 0,1 -> TA, wv 2,3 -> TB.
__global__ __launch_bounds__(256) void k_gemm1(const float* __restrict__ x,
                                               const __bf16* __restrict__ Wp,
                                               __bf16* __restrict__ TA,
                                               __bf16* __restrict__ TB) {
    __shared__ __bf16 As[64 * PAD];
    int tid = threadIdx.x;
    int wv = tid >> 6, lane = tid & 63;
    int quad = lane >> 4, l16 = lane & 15;
    long m0 = (long)blockIdx.x * 64;

    int srow = tid >> 2;            // 0..63
    int scol = (tid & 3) * 8;       // 0,8,16,24
    long grow = m0 + srow; if (grow > NN - 1) grow = NN - 1;
    const float* xrow = x + grow * NF;

    f32x4 acc[4][4];
#pragma unroll
    for (int a = 0; a < 4; a++)
#pragma unroll
        for (int b = 0; b < 4; b++) acc[a][b] = (f32x4)0.f;

    float4 p0 = *(const float4*)(xrow + scol);
    float4 p1 = *(const float4*)(xrow + scol + 4);

    for (int kc = 0; kc < 16; kc++) {
        union { bf16x8 v; __bf16 e[8]; } u;
        u.e[0] = (__bf16)p0.x; u.e[1] = (__bf16)p0.y;
        u.e[2] = (__bf16)p0.z; u.e[3] = (__bf16)p0.w;
        u.e[4] = (__bf16)p1.x; u.e[5] = (__bf16)p1.y;
        u.e[6] = (__bf16)p1.z; u.e[7] = (__bf16)p1.w;
        *(bf16x8*)&As[srow * PAD + scol] = u.v;
        __syncthreads();
        if (kc < 15) {
            p0 = *(const float4*)(xrow + (kc + 1) * 32 + scol);
            p1 = *(const float4*)(xrow + (kc + 1) * 32 + scol + 4);
        }
        bf16x8 bfr[4];
#pragma unroll
        for (int nt = 0; nt < 4; nt++)
            bfr[nt] = *(const bf16x8*)(Wp + (((long)(wv * 4 + nt) * 16 + kc) * 64 + lane) * 8);
#pragma unroll
        for (int mt = 0; mt < 4; mt++) {
            bf16x8 af = *(const bf16x8*)&As[(mt * 16 + l16) * PAD + quad * 8];
#pragma unroll
            for (int nt = 0; nt < 4; nt++)
                acc[mt][nt] = __builtin_amdgcn_mfma_f32_16x16x32_bf16(af, bfr[nt], acc[mt][nt], 0, 0, 0);
        }
        __syncthreads();
    }
    __bf16* T = (wv < 2) ? TA : TB;
    int c0 = (wv & 1) * 64;
#pragma unroll
    for (int mt = 0; mt < 4; mt++)
#pragma unroll
        for (int r = 0; r < 4; r++) {
            long gr = m0 + mt * 16 + quad * 4 + r;
            if (gr < NN) {
#pragma unroll
                for (int nt = 0; nt < 4; nt++)
                    T[gr * 128 + c0 + nt * 16 + l16] = (__bf16)acc[mt][nt][r];
            }
        }
}

// ---------------- SpMM half (layer 1): o = bf16(relu(adj @ T + bias)), 128-wide ----------------
__global__ __launch_bounds__(256) void k_spmm_h(const __bf16* __restrict__ T,
                                                const int2* __restrict__ sedge,
                                                const int* __restrict__ row_ptr,
                                                const int* __restrict__ deg,
                                                const float* __restrict__ bias,
                                                __bf16* __restrict__ o) {
    int wave = threadIdx.x >> 6, lane = threadIdx.x & 63;
    int n = blockIdx.x * 4 + wave;
    if (n >= NN) return;
    int i = row_ptr[n];
    int end = i + deg[n];
    float a0 = 0.f, a1 = 0.f;
    const bf16x2* base = (const bf16x2*)T;  // row stride 64 bf16x2
    for (; i + 8 <= end; i += 8) {
        int2 e0 = sedge[i], e1 = sedge[i+1], e2 = sedge[i+2], e3 = sedge[i+3];
        int2 e4 = sedge[i+4], e5 = sedge[i+5], e6 = sedge[i+6], e7 = sedge[i+7];
        bf16x2 v0 = base[(long)e0.x * 64 + lane];
        bf16x2 v1 = base[(long)e1.x * 64 + lane];
        bf16x2 v2 = base[(long)e2.x * 64 + lane];
        bf16x2 v3 = base[(long)e3.x * 64 + lane];
        bf16x2 v4 = base[(long)e4.x * 64 + lane];
        bf16x2 v5 = base[(long)e5.x * 64 + lane];
        bf16x2 v6 = base[(long)e6.x * 64 + lane];
        bf16x2 v7 = base[(long)e7.x * 64 + lane];
        a0 += __uint_as_float(e0.y) * (float)v0[0] + __uint_as_float(e1.y) * (float)v1[0]
            + __uint_as_float(e2.y) * (float)v2[0] + __uint_as_float(e3.y) * (float)v3[0]
            + __uint_as_float(e4.y) * (float)v4[0] + __uint_as_float(e5.y) * (float)v5[0]
            + __uint_as_float(e6.y) * (float)v6[0] + __uint_as_float(e7.y) * (float)v7[0];
        a1 += __uint_as_float(e0.y) * (float)v0[1] + __uint_as_float(e1.y) * (float)v1[1]
            + __uint_as_float(e2.y) * (float)v2[1] + __uint_as_float(e3.y) * (float)v3[1]
            + __uint_as_float(e4.y) * (float)v4[1] + __uint_as_float(e5.y) * (float)v5[1]
            + __uint_as_float(e6.y) * (float)v6[1] + __uint_as_float(e7.y) * (float)v7[1];
    }
    for (; i < end; i++) {
        int2 e = sedge[i];
        float w = __uint_as_float(e.y);
        bf16x2 v = base[(long)e.x * 64 + lane];
        a0 += w * (float)v[0]; a1 += w * (float)v[1];
    }
    float2 b = ((const float2*)bias)[lane];
    bf16x2 ov;
    ov[0] = (__bf16)fmaxf(a0 + b.x, 0.f);
    ov[1] = (__bf16)fmaxf(a1 + b.y, 0.f);
    ((bf16x2*)o)[(long)n * 64 + lane] = ov;
}

// ---------------- GEMM2 (MFMA): HMb = bf16(h @ [W_mu|W_lv]), h stored as two halves ----------------
// BM=128, BN=128, BK=32. 4 waves in 2x2.
__global__ __launch_bounds__(256) void k_gemm2(const __bf16* __restrict__ hA,
                                               const __bf16* __restrict__ hB,
                                               const __bf16* __restrict__ Wp,
                                               __bf16* __restrict__ HMb) {
    __shared__ __bf16 As[128 * PAD];
    int tid = threadIdx.x;
    int wv = tid >> 6, lane = tid & 63;
    int quad = lane >> 4, l16 = lane & 15;
    int wr = (wv >> 1) * 64, wc = (wv & 1) * 64;
    long m0 = (long)blockIdx.x * 128;

    int srow = tid >> 1;            // 0..127
    int scol = (tid & 1) * 16;      // 0,16
    long grow = m0 + srow; if (grow > NN - 1) grow = NN - 1;

    f32x4 acc[4][4];
#pragma unroll
    for (int a = 0; a < 4; a++)
#pragma unroll
        for (int b = 0; b < 4; b++) acc[a][b] = (f32x4)0.f;

    // k slice for kc: kc<4 -> hA cols kc*32.., kc>=4 -> hB cols (kc-4)*32..
    const __bf16* rA = hA + grow * 128;
    const __bf16* rB = hB + grow * 128;
    bf16x8 p0 = *(const bf16x8*)(rA + scol);
    bf16x8 p1 = *(const bf16x8*)(rA + scol + 8);

    for (int kc = 0; kc < 8; kc++) {
        *(bf16x8*)&As[srow * PAD + scol] = p0;
        *(bf16x8*)&As[srow * PAD + scol + 8] = p1;
        __syncthreads();
        if (kc < 7) {
            const __bf16* nxt = ((kc + 1) < 4 ? rA : rB) + ((kc + 1) & 3) * 32;
            p0 = *(const bf16x8*)(nxt + scol);
            p1 = *(const bf16x8*)(nxt + scol + 8);
        }
        bf16x8 bfr[4];
#pragma unroll
        for (int nt = 0; nt < 4; nt++) {
            int ntg = (wc >> 4) + nt;
            bfr[nt] = *(const bf16x8*)(Wp + (((long)ntg * 8 + kc) * 64 + lane) * 8);
        }
#pragma unroll
        for (int mt = 0; mt < 4; mt++) {
            bf16x8 af = *(const bf16x8*)&As[(wr + mt * 16 + l16) * PAD + quad * 8];
#pragma unroll
            for (int nt = 0; nt < 4; nt++)
                acc[mt][nt] = __builtin_amdgcn_mfma_f32_16x16x32_bf16(af, bfr[nt], acc[mt][nt], 0, 0, 0);
        }
        __syncthreads();
    }
#pragma unroll
    for (int mt = 0; mt < 4; mt++)
#pragma unroll
        for (int r = 0; r < 4; r++) {
            long gr = m0 + wr + mt * 16 + quad * 4 + r;
            if (gr < NN) {
#pragma unroll
                for (int nt = 0; nt < 4; nt++)
                    HMb[gr * 128 + wc + nt * 16 + l16] = (__bf16)acc[mt][nt][r];
            }
        }
}

// ---------------- SpMM2 + bias: out = [adj@HM + b_mu ; adj@HL + b_lv] ----------------
__global__ __launch_bounds__(256) void k_spmm2(const __bf16* __restrict__ HMb,
                                               const int2* __restrict__ sedge,
                                               const int* __restrict__ row_ptr,
                                               const int* __restrict__ deg,
                                               const float* __restrict__ bmu,
                                               const float* __restrict__ blv,
                                               float* __restrict__ out) {
    int wave = threadIdx.x >> 6, lane = threadIdx.x & 63;
    int n = blockIdx.x * 4 + wave;
    if (n >= NN) return;
    int i = row_ptr[n];
    int end = i + deg[n];
    float a0 = 0.f, a1 = 0.f;
    const bf16x2* base = (const bf16x2*)HMb;  // row stride 64 bf16x2
    for (; i + 8 <= end; i += 8) {
        int2 e0 = sedge[i], e1 = sedge[i+1], e2 = sedge[i+2], e3 = sedge[i+3];
        int2 e4 = sedge[i+4], e5 = sedge[i+5], e6 = sedge[i+6], e7 = sedge[i+7];
        bf16x2 v0 = base[(long)e0.x * 64 + lane];
        bf16x2 v1 = base[(long)e1.x * 64 + lane];
        bf16x2 v2 = base[(long)e2.x * 64 + lane];
        bf16x2 v3 = base[(long)e3.x * 64 + lane];
        bf16x2 v4 = base[(long)e4.x * 64 + lane];
        bf16x2 v5 = base[(long)e5.x * 64 + lane];
        bf16x2 v6 = base[(long)e6.x * 64 + lane];
        bf16x2 v7 = base[(long)e7.x * 64 + lane];
        a0 += __uint_as_float(e0.y) * (float)v0[0] + __uint_as_float(e1.y) * (float)v1[0]
            + __uint_as_float(e2.y) * (float)v2[0] + __uint_as_float(e3.y) * (float)v3[0]
            + __uint_as_float(e4.y) * (float)v4[0] + __uint_as_float(e5.y) * (float)v5[0]
            + __uint_as_float(e6.y) * (float)v6[0] + __uint_as_float(e7.y) * (float)v7[0];
        a1 += __uint_as_float(e0.y) * (float)v0[1] + __uint_as_float(e1.y) * (float)v1[1]
            + __uint_as_float(e2.y) * (float)v2[1] + __uint_as_float(e3.y) * (float)v3[1]
            + __uint_as_float(e4.y) * (float)v4[1] + __uint_as_float(e5.y) * (float)v5[1]
            + __uint_as_float(e6.y) * (float)v6[1] + __uint_as_float(e7.y) * (float)v7[1];
    }
    for (; i < end; i++) {
        int2 e = sedge[i];
        float w = __uint_as_float(e.y);
        bf16x2 v = base[(long)e.x * 64 + lane];
        a0 += w * (float)v[0]; a1 += w * (float)v[1];
    }
    if (lane < 32) {  // cols 0..63 -> mu
        float2 b = ((const float2*)bmu)[lane];
        float2 o = {a0 + b.x, a1 + b.y};
        ((float2*)out)[(long)n * 32 + lane] = o;
    } else {          // cols 64..127 -> logvar
        float2 b = ((const float2*)blv)[lane - 32];
        float2 o = {a0 + b.x, a1 + b.y};
        ((float2*)(out + (long)NN * NL))[(long)n * 32 + (lane - 32)] = o;
    }
}

extern "C" void kernel_launch(void* const* d_in, const int* in_sizes, int n_in,
                              void* d_out, int out_size, void* d_ws, size_t ws_size,
                              hipStream_t stream) {
    const float* x   = (const float*)d_in[0];
    const int*   ei  = (const int*)d_in[1];
    const float* ew  = (const float*)d_in[2];
    const float* W1  = (const float*)d_in[3];
    const float* b1  = (const float*)d_in[4];
    const float* Wmu = (const float*)d_in[5];
    const float* bmu = (const float*)d_in[6];
    const float* Wlv = (const float*)d_in[7];
    const float* blv = (const float*)d_in[8];
    float* out = (float*)d_out;

    char* ws = (char*)d_ws;
    __bf16* XWa    = (__bf16*)(ws);                  // NN*128 bf16 (25.6 MB)
    __bf16* XWb2   = (__bf16*)(ws + 25600000);       // NN*128 bf16
    __bf16* hA     = (__bf16*)(ws + 51200000);       // NN*128 bf16
    __bf16* hB     = (__bf16*)(ws + 76800000);       // NN*128 bf16
    __bf16* HMb    = (__bf16*)(ws + 102400000);      // NN*128 bf16
    int2*  sedge   = (int2*) (ws + 128000000);       // NE * 8 B (25.6 MB)
    int*   deg     = (int*)  (ws + 153600000);       // NN
    int*   row_ptr = (int*)  (ws + 154000000);       // NN
    int*   bcur    = (int*)  (ws + 154400000);       // NBKT
    int*   bsum    = (int*)  (ws + 154800000);       // NB_SCAN
    int*   bstart  = (int*)  (ws + 154810000);       // NBKT+1 (inside old slack)
    __bf16* Wp1    = (__bf16*)(ws + 154900000);      // 131072 bf16
    __bf16* Wp2    = (__bf16*)(ws + 155200000);      // 32768 bf16

    // CSR-build staging aliases buffers that are only live AFTER the build:
    int2* stage_sw = (int2*)XWa;                     // 25.6 MB, dead before k_gemm1
    int*  stage_p  = (int*)hA;                       // 12.8 MB, dead before k_spmm_h
    int*  rank     = (int*)XWb2;                     // 12.8 MB, dead before k_gemm1

    const int* esrc = ei;
    const int* edst = ei + NE;

    hipMemsetAsync(deg, 0, NN * sizeof(int), stream);

    // weight packing
    k_packW1<<<dim3(512), dim3(256), 0, stream>>>(W1, Wp1);
    k_packW2<<<dim3(128), dim3(256), 0, stream>>>(Wmu, Wlv, Wp2);

    // CSR build: histogram+rank -> scan -> bucket-partition -> localized scatter
    k_hist_rank<<<dim3((NE + 255) / 256), dim3(256), 0, stream>>>(edst, deg, rank);
    k_blocksum<<<dim3(NB_SCAN), dim3(256), 0, stream>>>(deg, bsum);
    k_scan_partials<<<dim3(1), dim3(512), 0, stream>>>(bsum);
    k_scan_final<<<dim3(NB_SCAN), dim3(256), 0, stream>>>(deg, bsum, row_ptr);
    k_binit<<<dim3(1), dim3(128), 0, stream>>>(row_ptr, bstart, bcur);
    k_bucket<<<dim3(NE / 1024), dim3(256), 0, stream>>>(esrc, edst, (const int*)ew,
                                                        rank, row_ptr, bcur,
                                                        stage_sw, stage_p);
    k_scatter2<<<dim3(NBKT * CPB), dim3(256), 0, stream>>>(stage_sw, stage_p, bstart, sedge);

    // layer 1
    k_gemm1<<<dim3((NN + 63) / 64), dim3(256), 0, stream>>>(x, Wp1, XWa, XWb2);
    k_spmm_h<<<dim3((NN + 3) / 4), dim3(256), 0, stream>>>(XWa, sedge, row_ptr, deg, b1, hA);
    k_spmm_h<<<dim3((NN + 3) / 4), dim3(256), 0, stream>>>(XWb2, sedge, row_ptr, deg, b1 + 128, hB);

    // layer 2
    k_gemm2<<<dim3((NN + 127) / 128), dim3(256), 0, stream>>>(hA, hB, Wp2, HMb);
    k_spmm2<<<dim3((NN + 3) / 4), dim3(256), 0, stream>>>(HMb, sedge, row_ptr, deg, bmu, blv, out);
}

// Round 2
// 847.321 us; speedup vs baseline: 1.1761x; 1.1298x over previous
//
#include <hip/hip_runtime.h>
#include <hip/hip_bf16.h>

#define NN 100000
#define NE 3200000
#define NF 512
#define NH 256
#define NL 64
#define PAD 40        // LDS row stride in bf16 elems

#define NBKT 256      // dst-range buckets
#define NPB 391       // ceil(NN/NBKT) nodes per bucket
#define CAP 13500     // staging capacity per bucket (mean 12512, sigma ~112)

typedef __bf16 bf16x8 __attribute__((ext_vector_type(8)));
typedef __bf16 bf16x4 __attribute__((ext_vector_type(4)));
typedef __bf16 bf16x2 __attribute__((ext_vector_type(2)));
typedef float  f32x4  __attribute__((ext_vector_type(4)));

// ---------------- CSR build (atomic-light, bucket-local) ----------------
// bcur is padded: counter for bucket b lives at bcur[b*16] (one 64B line each).
__global__ void k_binit2(int* __restrict__ bcur) {
    int t = threadIdx.x;          // 256 threads
    bcur[t * 16] = t * CAP;
}

// Phase 1: partition edges into 256 dst-range buckets (fixed-capacity slots).
// Per-block LDS counting + one global reservation atomic per bucket per block.
__global__ __launch_bounds__(256) void k_bucket0(const int* __restrict__ src,
                                                 const int* __restrict__ dst,
                                                 const int* __restrict__ wbits,
                                                 int* __restrict__ bcur,
                                                 int2* __restrict__ stage_sw,
                                                 int* __restrict__ stage_d) {
    __shared__ int cnt[NBKT];
    __shared__ int base[NBKT];
    int tid = threadIdx.x;
    cnt[tid] = 0;
    __syncthreads();
    int e0 = blockIdx.x * 1024;   // NE % 1024 == 0, no bounds check
    int ss[4], ww[4], dd[4], lr[4], bb[4];
#pragma unroll
    for (int k = 0; k < 4; k++) {
        int e = e0 + k * 256 + tid;
        int d = dst[e];
        ss[k] = src[e];
        ww[k] = wbits[e];
        dd[k] = d;
        bb[k] = (int)((unsigned)d / NPB);
        lr[k] = atomicAdd(&cnt[bb[k]], 1);
    }
    __syncthreads();
    base[tid] = atomicAdd(&bcur[tid * 16], cnt[tid]);
    __syncthreads();
#pragma unroll
    for (int k = 0; k < 4; k++) {
        int pos = base[bb[k]] + lr[k];
        stage_sw[pos] = make_int2(ss[k], ww[k]);
        stage_d[pos] = dd[k];
    }
}

// Exclusive scan of bucket fills -> bstart (CSR base per bucket, since buckets
// are dst-contiguous the staged order matches final CSR bucket order).
__global__ void k_bscan(const int* __restrict__ bcur, int* __restrict__ bstart) {
    __shared__ int s[NBKT];
    int t = threadIdx.x;          // 256 threads
    int v = bcur[t * 16] - t * CAP;
    s[t] = v;
    __syncthreads();
    for (int off = 1; off < NBKT; off <<= 1) {
        int a = (t >= off) ? s[t - off] : 0;
        __syncthreads();
        s[t] += a;
        __syncthreads();
    }
    bstart[t] = s[t] - v;         // exclusive
    if (t == NBKT - 1) bstart[NBKT] = s[t];
}

// Phase 2: one WG per bucket. LDS deg-histogram (391 counters), local scan ->
// row offsets, write deg/row_ptr coalesced, then scatter edges into the
// bucket's own contiguous ~100KB sedge region (L2-local, LDS-atomic ranks).
__global__ __launch_bounds__(512) void k_build(const int2* __restrict__ stage_sw,
                                               const int* __restrict__ stage_d,
                                               const int* __restrict__ bcur,
                                               const int* __restrict__ bstart,
                                               int* __restrict__ deg,
                                               int* __restrict__ row_ptr,
                                               int2* __restrict__ sedge) {
    __shared__ int hist[NPB];
    __shared__ int roff[NPB + 1];
    int b = blockIdx.x;
    int t = threadIdx.x;
    int n0 = b * NPB;
    int nb = NN - n0; if (nb > NPB) nb = NPB;
    int s0 = b * CAP;
    int fill = bcur[b * 16] - s0;

    for (int i = t; i < nb; i += 512) hist[i] = 0;
    __syncthreads();
    for (int i = t; i < fill; i += 512)
        atomicAdd(&hist[stage_d[s0 + i] - n0], 1);
    __syncthreads();
    if (t == 0) {
        int acc = 0;
        for (int i = 0; i < nb; i++) { roff[i] = acc; acc += hist[i]; }
        roff[nb] = acc;
    }
    __syncthreads();
    int base = bstart[b];
    for (int i = t; i < nb; i += 512) {
        deg[n0 + i] = hist[i];
        row_ptr[n0 + i] = base + roff[i];
    }
    __syncthreads();
    for (int i = t; i < nb; i += 512) hist[i] = 0;   // reuse as cursor
    __syncthreads();
    for (int i = t; i < fill; i += 512) {
        int d = stage_d[s0 + i] - n0;
        int r = atomicAdd(&hist[d], 1);
        sedge[base + roff[d] + r] = stage_sw[s0 + i];
    }
}

// ---------------- weight packing into MFMA B-fragment order ----------------
__global__ void k_packW1(const float* __restrict__ W, __bf16* __restrict__ P) {
    int i = blockIdx.x * 256 + threadIdx.x;       // 131072 = 16nt * 16kc * 64 * 8
    int j = i & 7, l = (i >> 3) & 63, kc = (i >> 9) & 15, nt = i >> 13;
    int k = kc * 32 + (l >> 4) * 8 + j;
    int n = nt * 16 + (l & 15);
    P[i] = (__bf16)W[k * NH + n];
}

__global__ void k_packW2(const float* __restrict__ Wmu, const float* __restrict__ Wlv,
                         __bf16* __restrict__ P) {
    int i = blockIdx.x * 256 + threadIdx.x;       // 32768 = 8nt * 8kc * 64 * 8
    int j = i & 7, l = (i >> 3) & 63, kc = (i >> 9) & 7, nt = i >> 12;
    int k = kc * 32 + (l >> 4) * 8 + j;
    int n = nt * 16 + (l & 15);
    float v = (n < NL) ? Wmu[k * NL + n] : Wlv[k * NL + (n - NL)];
    P[i] = (__bf16)v;
}

// ---------------- GEMM1 (MFMA): XW split into two column-half tables ----------------
// BM=64, BN=256, BK=32. wave wv -> cols [wv*64, wv*64+64); wv 0,1 -> TA, wv 2,3 -> TB.
__global__ __launch_bounds__(256) void k_gemm1(const float* __restrict__ x,
                                               const __bf16* __restrict__ Wp,
                                               __bf16* __restrict__ TA,
                                               __bf16* __restrict__ TB) {
    __shared__ __bf16 As[64 * PAD];
    int tid = threadIdx.x;
    int wv = tid >> 6, lane = tid & 63;
    int quad = lane >> 4, l16 = lane & 15;
    long m0 = (long)blockIdx.x * 64;

    int srow = tid >> 2;            // 0..63
    int scol = (tid & 3) * 8;       // 0,8,16,24
    long grow = m0 + srow; if (grow > NN - 1) grow = NN - 1;
    const float* xrow = x + grow * NF;

    f32x4 acc[4][4];
#pragma unroll
    for (int a = 0; a < 4; a++)
#pragma unroll
        for (int b = 0; b < 4; b++) acc[a][b] = (f32x4)0.f;

    float4 p0 = *(const float4*)(xrow + scol);
    float4 p1 = *(const float4*)(xrow + scol + 4);

    for (int kc = 0; kc < 16; kc++) {
        union { bf16x8 v; __bf16 e[8]; } u;
        u.e[0] = (__bf16)p0.x; u.e[1] = (__bf16)p0.y;
        u.e[2] = (__bf16)p0.z; u.e[3] = (__bf16)p0.w;
        u.e[4] = (__bf16)p1.x; u.e[5] = (__bf16)p1.y;
        u.e[6] = (__bf16)p1.z; u.e[7] = (__bf16)p1.w;
        *(bf16x8*)&As[srow * PAD + scol] = u.v;
        __syncthreads();
        if (kc < 15) {
            p0 = *(const float4*)(xrow + (kc + 1) * 32 + scol);
            p1 = *(const float4*)(xrow + (kc + 1) * 32 + scol + 4);
        }
        bf16x8 bfr[4];
#pragma unroll
        for (int nt = 0; nt < 4; nt++)
            bfr[nt] = *(const bf16x8*)(Wp + (((long)(wv * 4 + nt) * 16 + kc) * 64 + lane) * 8);
#pragma unroll
        for (int mt = 0; mt < 4; mt++) {
            bf16x8 af = *(const bf16x8*)&As[(mt * 16 + l16) * PAD + quad * 8];
#pragma unroll
            for (int nt = 0; nt < 4; nt++)
                acc[mt][nt] = __builtin_amdgcn_mfma_f32_16x16x32_bf16(af, bfr[nt], acc[mt][nt], 0, 0, 0);
        }
        __syncthreads();
    }
    __bf16* T = (wv < 2) ? TA : TB;
    int c0 = (wv & 1) * 64;
#pragma unroll
    for (int mt = 0; mt < 4; mt++)
#pragma unroll
        for (int r = 0; r < 4; r++) {
            long gr = m0 + mt * 16 + quad * 4 + r;
            if (gr < NN) {
#pragma unroll
                for (int nt = 0; nt < 4; nt++)
                    T[gr * 128 + c0 + nt * 16 + l16] = (__bf16)acc[mt][nt][r];
            }
        }
}

// ---------------- SpMM half (layer 1): o = bf16(relu(adj @ T + bias)), 128-wide ----------------
__global__ __launch_bounds__(256) void k_spmm_h(const __bf16* __restrict__ T,
                                                const int2* __restrict__ sedge,
                                                const int* __restrict__ row_ptr,
                                                const int* __restrict__ deg,
                                                const float* __restrict__ bias,
                                                __bf16* __restrict__ o) {
    int wave = threadIdx.x >> 6, lane = threadIdx.x & 63;
    int n = blockIdx.x * 4 + wave;
    if (n >= NN) return;
    int i = row_ptr[n];
    int end = i + deg[n];
    float a0 = 0.f, a1 = 0.f;
    const bf16x2* base = (const bf16x2*)T;  // row stride 64 bf16x2
    for (; i + 8 <= end; i += 8) {
        int2 e0 = sedge[i], e1 = sedge[i+1], e2 = sedge[i+2], e3 = sedge[i+3];
        int2 e4 = sedge[i+4], e5 = sedge[i+5], e6 = sedge[i+6], e7 = sedge[i+7];
        bf16x2 v0 = base[(long)e0.x * 64 + lane];
        bf16x2 v1 = base[(long)e1.x * 64 + lane];
        bf16x2 v2 = base[(long)e2.x * 64 + lane];
        bf16x2 v3 = base[(long)e3.x * 64 + lane];
        bf16x2 v4 = base[(long)e4.x * 64 + lane];
        bf16x2 v5 = base[(long)e5.x * 64 + lane];
        bf16x2 v6 = base[(long)e6.x * 64 + lane];
        bf16x2 v7 = base[(long)e7.x * 64 + lane];
        a0 += __uint_as_float(e0.y) * (float)v0[0] + __uint_as_float(e1.y) * (float)v1[0]
            + __uint_as_float(e2.y) * (float)v2[0] + __uint_as_float(e3.y) * (float)v3[0]
            + __uint_as_float(e4.y) * (float)v4[0] + __uint_as_float(e5.y) * (float)v5[0]
            + __uint_as_float(e6.y) * (float)v6[0] + __uint_as_float(e7.y) * (float)v7[0];
        a1 += __uint_as_float(e0.y) * (float)v0[1] + __uint_as_float(e1.y) * (float)v1[1]
            + __uint_as_float(e2.y) * (float)v2[1] + __uint_as_float(e3.y) * (float)v3[1]
            + __uint_as_float(e4.y) * (float)v4[1] + __uint_as_float(e5.y) * (float)v5[1]
            + __uint_as_float(e6.y) * (float)v6[1] + __uint_as_float(e7.y) * (float)v7[1];
    }
    for (; i < end; i++) {
        int2 e = sedge[i];
        float w = __uint_as_float(e.y);
        bf16x2 v = base[(long)e.x * 64 + lane];
        a0 += w * (float)v[0]; a1 += w * (float)v[1];
    }
    float2 b = ((const float2*)bias)[lane];
    bf16x2 ov;
    ov[0] = (__bf16)fmaxf(a0 + b.x, 0.f);
    ov[1] = (__bf16)fmaxf(a1 + b.y, 0.f);
    ((bf16x2*)o)[(long)n * 64 + lane] = ov;
}

// ---------------- GEMM2 (MFMA): HMb = bf16(h @ [W_mu|W_lv]), h stored as two halves ----------------
// BM=128, BN=128, BK=32. 4 waves in 2x2.
__global__ __launch_bounds__(256) void k_gemm2(const __bf16* __restrict__ hA,
                                               const __bf16* __restrict__ hB,
                                               const __bf16* __restrict__ Wp,
                                               __bf16* __restrict__ HMb) {
    __shared__ __bf16 As[128 * PAD];
    int tid = threadIdx.x;
    int wv = tid >> 6, lane = tid & 63;
    int quad = lane >> 4, l16 = lane & 15;
    int wr = (wv >> 1) * 64, wc = (wv & 1) * 64;
    long m0 = (long)blockIdx.x * 128;

    int srow = tid >> 1;            // 0..127
    int scol = (tid & 1) * 16;      // 0,16
    long grow = m0 + srow; if (grow > NN - 1) grow = NN - 1;

    f32x4 acc[4][4];
#pragma unroll
    for (int a = 0; a < 4; a++)
#pragma unroll
        for (int b = 0; b < 4; b++) acc[a][b] = (f32x4)0.f;

    // k slice for kc: kc<4 -> hA cols kc*32.., kc>=4 -> hB cols (kc-4)*32..
    const __bf16* rA = hA + grow * 128;
    const __bf16* rB = hB + grow * 128;
    bf16x8 p0 = *(const bf16x8*)(rA + scol);
    bf16x8 p1 = *(const bf16x8*)(rA + scol + 8);

    for (int kc = 0; kc < 8; kc++) {
        *(bf16x8*)&As[srow * PAD + scol] = p0;
        *(bf16x8*)&As[srow * PAD + scol + 8] = p1;
        __syncthreads();
        if (kc < 7) {
            const __bf16* nxt = ((kc + 1) < 4 ? rA : rB) + ((kc + 1) & 3) * 32;
            p0 = *(const bf16x8*)(nxt + scol);
            p1 = *(const bf16x8*)(nxt + scol + 8);
        }
        bf16x8 bfr[4];
#pragma unroll
        for (int nt = 0; nt < 4; nt++) {
            int ntg = (wc >> 4) + nt;
            bfr[nt] = *(const bf16x8*)(Wp + (((long)ntg * 8 + kc) * 64 + lane) * 8);
        }
#pragma unroll
        for (int mt = 0; mt < 4; mt++) {
            bf16x8 af = *(const bf16x8*)&As[(wr + mt * 16 + l16) * PAD + quad * 8];
#pragma unroll
            for (int nt = 0; nt < 4; nt++)
                acc[mt][nt] = __builtin_amdgcn_mfma_f32_16x16x32_bf16(af, bfr[nt], acc[mt][nt], 0, 0, 0);
        }
        __syncthreads();
    }
#pragma unroll
    for (int mt = 0; mt < 4; mt++)
#pragma unroll
        for (int r = 0; r < 4; r++) {
            long gr = m0 + wr + mt * 16 + quad * 4 + r;
            if (gr < NN) {
#pragma unroll
                for (int nt = 0; nt < 4; nt++)
                    HMb[gr * 128 + wc + nt * 16 + l16] = (__bf16)acc[mt][nt][r];
            }
        }
}

// ---------------- SpMM2 + bias: out = [adj@HM + b_mu ; adj@HL + b_lv] ----------------
__global__ __launch_bounds__(256) void k_spmm2(const __bf16* __restrict__ HMb,
                                               const int2* __restrict__ sedge,
                                               const int* __restrict__ row_ptr,
                                               const int* __restrict__ deg,
                                               const float* __restrict__ bmu,
                                               const float* __restrict__ blv,
                                               float* __restrict__ out) {
    int wave = threadIdx.x >> 6, lane = threadIdx.x & 63;
    int n = blockIdx.x * 4 + wave;
    if (n >= NN) return;
    int i = row_ptr[n];
    int end = i + deg[n];
    float a0 = 0.f, a1 = 0.f;
    const bf16x2* base = (const bf16x2*)HMb;  // row stride 64 bf16x2
    for (; i + 8 <= end; i += 8) {
        int2 e0 = sedge[i], e1 = sedge[i+1], e2 = sedge[i+2], e3 = sedge[i+3];
        int2 e4 = sedge[i+4], e5 = sedge[i+5], e6 = sedge[i+6], e7 = sedge[i+7];
        bf16x2 v0 = base[(long)e0.x * 64 + lane];
        bf16x2 v1 = base[(long)e1.x * 64 + lane];
        bf16x2 v2 = base[(long)e2.x * 64 + lane];
        bf16x2 v3 = base[(long)e3.x * 64 + lane];
        bf16x2 v4 = base[(long)e4.x * 64 + lane];
        bf16x2 v5 = base[(long)e5.x * 64 + lane];
        bf16x2 v6 = base[(long)e6.x * 64 + lane];
        bf16x2 v7 = base[(long)e7.x * 64 + lane];
        a0 += __uint_as_float(e0.y) * (float)v0[0] + __uint_as_float(e1.y) * (float)v1[0]
            + __uint_as_float(e2.y) * (float)v2[0] + __uint_as_float(e3.y) * (float)v3[0]
            + __uint_as_float(e4.y) * (float)v4[0] + __uint_as_float(e5.y) * (float)v5[0]
            + __uint_as_float(e6.y) * (float)v6[0] + __uint_as_float(e7.y) * (float)v7[0];
        a1 += __uint_as_float(e0.y) * (float)v0[1] + __uint_as_float(e1.y) * (float)v1[1]
            + __uint_as_float(e2.y) * (float)v2[1] + __uint_as_float(e3.y) * (float)v3[1]
            + __uint_as_float(e4.y) * (float)v4[1] + __uint_as_float(e5.y) * (float)v5[1]
            + __uint_as_float(e6.y) * (float)v6[1] + __uint_as_float(e7.y) * (float)v7[1];
    }
    for (; i < end; i++) {
        int2 e = sedge[i];
        float w = __uint_as_float(e.y);
        bf16x2 v = base[(long)e.x * 64 + lane];
        a0 += w * (float)v[0]; a1 += w * (float)v[1];
    }
    if (lane < 32) {  // cols 0..63 -> mu
        float2 b = ((const float2*)bmu)[lane];
        float2 o = {a0 + b.x, a1 + b.y};
        ((float2*)out)[(long)n * 32 + lane] = o;
    } else {          // cols 64..127 -> logvar
        float2 b = ((const float2*)blv)[lane - 32];
        float2 o = {a0 + b.x, a1 + b.y};
        ((float2*)(out + (long)NN * NL))[(long)n * 32 + (lane - 32)] = o;
    }
}

extern "C" void kernel_launch(void* const* d_in, const int* in_sizes, int n_in,
                              void* d_out, int out_size, void* d_ws, size_t ws_size,
                              hipStream_t stream) {
    const float* x   = (const float*)d_in[0];
    const int*   ei  = (const int*)d_in[1];
    const float* ew  = (const float*)d_in[2];
    const float* W1  = (const float*)d_in[3];
    const float* b1  = (const float*)d_in[4];
    const float* Wmu = (const float*)d_in[5];
    const float* bmu = (const float*)d_in[6];
    const float* Wlv = (const float*)d_in[7];
    const float* blv = (const float*)d_in[8];
    float* out = (float*)d_out;

    char* ws = (char*)d_ws;
    __bf16* XWa    = (__bf16*)(ws);                  // NN*128 bf16 (25.6 MB)
    __bf16* XWb2   = (__bf16*)(ws + 25600000);       // NN*128 bf16
    __bf16* hA     = (__bf16*)(ws + 51200000);       // NN*128 bf16
    __bf16* hB     = (__bf16*)(ws + 76800000);       // NN*128 bf16
    __bf16* HMb    = (__bf16*)(ws + 102400000);      // NN*128 bf16
    int2*  sedge   = (int2*) (ws + 128000000);       // NE * 8 B (25.6 MB)
    int*   deg     = (int*)  (ws + 153600000);       // NN
    int*   row_ptr = (int*)  (ws + 154000000);       // NN
    int*   bcur    = (int*)  (ws + 154400000);       // NBKT padded counters (16KB)
    int*   bstart  = (int*)  (ws + 154800000);       // NBKT+1
    __bf16* Wp1    = (__bf16*)(ws + 154900000);      // 131072 bf16
    __bf16* Wp2    = (__bf16*)(ws + 155200000);      // 32768 bf16

    // CSR-build staging aliases hA/hB (dead until k_spmm_h; CSR build runs first):
    int2* stage_sw = (int2*)(ws + 51200000);         // 256*13500*8 = 27.65 MB
    int*  stage_d  = (int*) (ws + 51200000 + (long)NBKT * CAP * 8);  // 13.8 MB

    const int* esrc = ei;
    const int* edst = ei + NE;

    // weight packing
    k_packW1<<<dim3(512), dim3(256), 0, stream>>>(W1, Wp1);
    k_packW2<<<dim3(128), dim3(256), 0, stream>>>(Wmu, Wlv, Wp2);

    // CSR build: bucket-partition -> bucket scan -> per-bucket deg/rank/scatter
    k_binit2<<<dim3(1), dim3(NBKT), 0, stream>>>(bcur);
    k_bucket0<<<dim3(NE / 1024), dim3(256), 0, stream>>>(esrc, edst, (const int*)ew,
                                                         bcur, stage_sw, stage_d);
    k_bscan<<<dim3(1), dim3(NBKT), 0, stream>>>(bcur, bstart);
    k_build<<<dim3(NBKT), dim3(512), 0, stream>>>(stage_sw, stage_d, bcur, bstart,
                                                  deg, row_ptr, sedge);

    // layer 1
    k_gemm1<<<dim3((NN + 63) / 64), dim3(256), 0, stream>>>(x, Wp1, XWa, XWb2);
    k_spmm_h<<<dim3((NN + 3) / 4), dim3(256), 0, stream>>>(XWa, sedge, row_ptr, deg, b1, hA);
    k_spmm_h<<<dim3((NN + 3) / 4), dim3(256), 0, stream>>>(XWb2, sedge, row_ptr, deg, b1 + 128, hB);

    // layer 2
    k_gemm2<<<dim3((NN + 127) / 128), dim3(256), 0, stream>>>(hA, hB, Wp2, HMb);
    k_spmm2<<<dim3((NN + 3) / 4), dim3(256), 0, stream>>>(HMb, sedge, row_ptr, deg, bmu, blv, out);
}

// Round 3
// 842.661 us; speedup vs baseline: 1.1826x; 1.0055x over previous
//
#include <hip/hip_runtime.h>
#include <hip/hip_bf16.h>

#define NN 100000
#define NE 3200000
#define NF 512
#define NH 256
#define NL 64
#define PAD 40        // LDS row stride in bf16 elems

#define NBKT 256      // dst-range buckets
#define NPB 391       // ceil(NN/NBKT) nodes per bucket
#define CAP 13500     // staging capacity per bucket (mean 12512, sigma ~112)
#define NCLS 16       // src classes for gather locality
#define DIVC 6250     // NN / NCLS

typedef __bf16 bf16x8 __attribute__((ext_vector_type(8)));
typedef __bf16 bf16x4 __attribute__((ext_vector_type(4)));
typedef __bf16 bf16x2 __attribute__((ext_vector_type(2)));
typedef float  f32x4  __attribute__((ext_vector_type(4)));

// ---------------- CSR build (atomic-light, bucket-local, src-class-sorted) ----------------
// bcur is padded: counter for bucket b lives at bcur[b*16] (one 64B line each).
__global__ void k_binit2(int* __restrict__ bcur) {
    int t = threadIdx.x;          // 256 threads
    bcur[t * 16] = t * CAP;
}

// Phase 1: partition edges into 256 dst-range buckets (fixed-capacity slots).
// Per-block LDS counting + one global reservation atomic per bucket per block.
// stage_d packs dst (17 bits) | src-class << 20.
__global__ __launch_bounds__(256) void k_bucket0(const int* __restrict__ src,
                                                 const int* __restrict__ dst,
                                                 const int* __restrict__ wbits,
                                                 int* __restrict__ bcur,
                                                 int2* __restrict__ stage_sw,
                                                 int* __restrict__ stage_d) {
    __shared__ int cnt[NBKT];
    __shared__ int base[NBKT];
    int tid = threadIdx.x;
    cnt[tid] = 0;
    __syncthreads();
    int e0 = blockIdx.x * 1024;   // NE % 1024 == 0, no bounds check
    int ss[4], ww[4], dd[4], lr[4], bb[4];
#pragma unroll
    for (int k = 0; k < 4; k++) {
        int e = e0 + k * 256 + tid;
        int d = dst[e];
        int s = src[e];
        ss[k] = s;
        ww[k] = wbits[e];
        int cls = (int)((unsigned)s / DIVC);
        dd[k] = d | (cls << 20);
        bb[k] = (int)((unsigned)d / NPB);
        lr[k] = atomicAdd(&cnt[bb[k]], 1);
    }
    __syncthreads();
    base[tid] = atomicAdd(&bcur[tid * 16], cnt[tid]);
    __syncthreads();
#pragma unroll
    for (int k = 0; k < 4; k++) {
        int pos = base[bb[k]] + lr[k];
        stage_sw[pos] = make_int2(ss[k], ww[k]);
        stage_d[pos] = dd[k];
    }
}

// Exclusive scan of bucket fills -> bstart (CSR base per bucket).
__global__ void k_bscan(const int* __restrict__ bcur, int* __restrict__ bstart) {
    __shared__ int s[NBKT];
    int t = threadIdx.x;          // 256 threads
    int v = bcur[t * 16] - t * CAP;
    s[t] = v;
    __syncthreads();
    for (int off = 1; off < NBKT; off <<= 1) {
        int a = (t >= off) ? s[t - off] : 0;
        __syncthreads();
        s[t] += a;
        __syncthreads();
    }
    bstart[t] = s[t] - v;         // exclusive
    if (t == NBKT - 1) bstart[NBKT] = s[t];
}

// Phase 2: one WG per bucket. 2-level LDS histogram [node][class] -> per-row
// edges grouped by src-class (gather locality in the SpMMs). Single scatter
// pass via LDS cursors into the bucket's contiguous sedge region.
__global__ __launch_bounds__(512) void k_build(const int2* __restrict__ stage_sw,
                                               const int* __restrict__ stage_d,
                                               const int* __restrict__ bcur,
                                               const int* __restrict__ bstart,
                                               int* __restrict__ deg,
                                               int* __restrict__ row_ptr,
                                               int2* __restrict__ sedge) {
    __shared__ int hist2[NPB * NCLS];    // counts -> absolute cursors
    __shared__ int sb[2][512];           // node-total scan buffer
    int b = blockIdx.x;
    int t = threadIdx.x;
    int n0 = b * NPB;
    int nb = NN - n0; if (nb > NPB) nb = NPB;
    int s0 = b * CAP;
    int fill = bcur[b * 16] - s0;

    for (int i = t; i < nb * NCLS; i += 512) hist2[i] = 0;
    __syncthreads();
    for (int i = t; i < fill; i += 512) {
        int v = stage_d[s0 + i];
        atomicAdd(&hist2[(v & 0xFFFFF) - n0 + ((v >> 20) * 0)], 1);  // placeholder
    }
    __syncthreads();
    // NOTE: the loop above must histogram [node][class]; rewritten below.
    // (kept simple: redo zero + correct pass)
    for (int i = t; i < nb * NCLS; i += 512) hist2[i] = 0;
    __syncthreads();
    for (int i = t; i < fill; i += 512) {
        int v = stage_d[s0 + i];
        int dn = (v & 0xFFFFF) - n0;
        int c = v >> 20;
        atomicAdd(&hist2[dn * NCLS + c], 1);
    }
    __syncthreads();
    // per-node totals
    int tot = 0;
    if (t < nb) {
#pragma unroll
        for (int c = 0; c < NCLS; c++) tot += hist2[t * NCLS + c];
    }
    sb[0][t] = (t < nb) ? tot : 0;
    __syncthreads();
    int cur = 0;
    for (int off = 1; off < 512; off <<= 1) {
        int nv = sb[cur][t] + ((t >= off) ? sb[cur][t - off] : 0);
        cur ^= 1;
        sb[cur][t] = nv;
        __syncthreads();
    }
    int base = bstart[b];
    if (t < nb) {
        int acc = base + sb[cur][t] - tot;   // exclusive node offset (absolute)
        deg[n0 + t] = tot;
        row_ptr[n0 + t] = acc;
        // convert hist2 row to absolute class cursors
#pragma unroll
        for (int c = 0; c < NCLS; c++) {
            int tmp = hist2[t * NCLS + c];
            hist2[t * NCLS + c] = acc;
            acc += tmp;
        }
    }
    __syncthreads();
    for (int i = t; i < fill; i += 512) {
        int v = stage_d[s0 + i];
        int dn = (v & 0xFFFFF) - n0;
        int c = v >> 20;
        int pos = atomicAdd(&hist2[dn * NCLS + c], 1);
        sedge[pos] = stage_sw[s0 + i];
    }
}

// ---------------- weight packing into MFMA B-fragment order ----------------
__global__ void k_packW1(const float* __restrict__ W, __bf16* __restrict__ P) {
    int i = blockIdx.x * 256 + threadIdx.x;       // 131072 = 16nt * 16kc * 64 * 8
    int j = i & 7, l = (i >> 3) & 63, kc = (i >> 9) & 15, nt = i >> 13;
    int k = kc * 32 + (l >> 4) * 8 + j;
    int n = nt * 16 + (l & 15);
    P[i] = (__bf16)W[k * NH + n];
}

__global__ void k_packW2(const float* __restrict__ Wmu, const float* __restrict__ Wlv,
                         __bf16* __restrict__ P) {
    int i = blockIdx.x * 256 + threadIdx.x;       // 32768 = 8nt * 8kc * 64 * 8
    int j = i & 7, l = (i >> 3) & 63, kc = (i >> 9) & 7, nt = i >> 12;
    int k = kc * 32 + (l >> 4) * 8 + j;
    int n = nt * 16 + (l & 15);
    float v = (n < NL) ? Wmu[k * NL + n] : Wlv[k * NL + (n - NL)];
    P[i] = (__bf16)v;
}

// ---------------- GEMM1 (MFMA): XW interleaved table NN x 256 ----------------
// BM=64, BN=256, BK=32. wave wv -> cols [wv*64, wv*64+64).
__global__ __launch_bounds__(256) void k_gemm1(const float* __restrict__ x,
                                               const __bf16* __restrict__ Wp,
                                               __bf16* __restrict__ T) {
    __shared__ __bf16 As[64 * PAD];
    int tid = threadIdx.x;
    int wv = tid >> 6, lane = tid & 63;
    int quad = lane >> 4, l16 = lane & 15;
    long m0 = (long)blockIdx.x * 64;

    int srow = tid >> 2;            // 0..63
    int scol = (tid & 3) * 8;       // 0,8,16,24
    long grow = m0 + srow; if (grow > NN - 1) grow = NN - 1;
    const float* xrow = x + grow * NF;

    f32x4 acc[4][4];
#pragma unroll
    for (int a = 0; a < 4; a++)
#pragma unroll
        for (int b = 0; b < 4; b++) acc[a][b] = (f32x4)0.f;

    float4 p0 = *(const float4*)(xrow + scol);
    float4 p1 = *(const float4*)(xrow + scol + 4);

    for (int kc = 0; kc < 16; kc++) {
        union { bf16x8 v; __bf16 e[8]; } u;
        u.e[0] = (__bf16)p0.x; u.e[1] = (__bf16)p0.y;
        u.e[2] = (__bf16)p0.z; u.e[3] = (__bf16)p0.w;
        u.e[4] = (__bf16)p1.x; u.e[5] = (__bf16)p1.y;
        u.e[6] = (__bf16)p1.z; u.e[7] = (__bf16)p1.w;
        *(bf16x8*)&As[srow * PAD + scol] = u.v;
        __syncthreads();
        if (kc < 15) {
            p0 = *(const float4*)(xrow + (kc + 1) * 32 + scol);
            p1 = *(const float4*)(xrow + (kc + 1) * 32 + scol + 4);
        }
        bf16x8 bfr[4];
#pragma unroll
        for (int nt = 0; nt < 4; nt++)
            bfr[nt] = *(const bf16x8*)(Wp + (((long)(wv * 4 + nt) * 16 + kc) * 64 + lane) * 8);
#pragma unroll
        for (int mt = 0; mt < 4; mt++) {
            bf16x8 af = *(const bf16x8*)&As[(mt * 16 + l16) * PAD + quad * 8];
#pragma unroll
            for (int nt = 0; nt < 4; nt++)
                acc[mt][nt] = __builtin_amdgcn_mfma_f32_16x16x32_bf16(af, bfr[nt], acc[mt][nt], 0, 0, 0);
        }
        __syncthreads();
    }
#pragma unroll
    for (int mt = 0; mt < 4; mt++)
#pragma unroll
        for (int r = 0; r < 4; r++) {
            long gr = m0 + mt * 16 + quad * 4 + r;
            if (gr < NN) {
#pragma unroll
                for (int nt = 0; nt < 4; nt++)
                    T[gr * 256 + wv * 64 + nt * 16 + l16] = (__bf16)acc[mt][nt][r];
            }
        }
}

// ---------------- SpMM layer 1 (merged 256-wide): h = bf16(relu(adj @ XW + b1)) ----------------
__global__ __launch_bounds__(256) void k_spmm_h(const __bf16* __restrict__ T,
                                                const int2* __restrict__ sedge,
                                                const int* __restrict__ row_ptr,
                                                const int* __restrict__ deg,
                                                const float* __restrict__ bias,
                                                __bf16* __restrict__ o) {
    int wave = threadIdx.x >> 6, lane = threadIdx.x & 63;
    int n = blockIdx.x * 4 + wave;
    if (n >= NN) return;
    int i = row_ptr[n];
    int end = i + deg[n];
    float a0 = 0.f, a1 = 0.f, a2 = 0.f, a3 = 0.f;
    const bf16x4* base = (const bf16x4*)T;  // row stride 64 bf16x4 (256 cols)
    for (; i + 8 <= end; i += 8) {
        int2 e0 = sedge[i], e1 = sedge[i+1], e2 = sedge[i+2], e3 = sedge[i+3];
        int2 e4 = sedge[i+4], e5 = sedge[i+5], e6 = sedge[i+6], e7 = sedge[i+7];
        bf16x4 v0 = base[(long)e0.x * 64 + lane];
        bf16x4 v1 = base[(long)e1.x * 64 + lane];
        bf16x4 v2 = base[(long)e2.x * 64 + lane];
        bf16x4 v3 = base[(long)e3.x * 64 + lane];
        bf16x4 v4 = base[(long)e4.x * 64 + lane];
        bf16x4 v5 = base[(long)e5.x * 64 + lane];
        bf16x4 v6 = base[(long)e6.x * 64 + lane];
        bf16x4 v7 = base[(long)e7.x * 64 + lane];
        float w0 = __uint_as_float(e0.y), w1 = __uint_as_float(e1.y);
        float w2 = __uint_as_float(e2.y), w3 = __uint_as_float(e3.y);
        float w4 = __uint_as_float(e4.y), w5 = __uint_as_float(e5.y);
        float w6 = __uint_as_float(e6.y), w7 = __uint_as_float(e7.y);
        a0 += w0*(float)v0[0] + w1*(float)v1[0] + w2*(float)v2[0] + w3*(float)v3[0]
            + w4*(float)v4[0] + w5*(float)v5[0] + w6*(float)v6[0] + w7*(float)v7[0];
        a1 += w0*(float)v0[1] + w1*(float)v1[1] + w2*(float)v2[1] + w3*(float)v3[1]
            + w4*(float)v4[1] + w5*(float)v5[1] + w6*(float)v6[1] + w7*(float)v7[1];
        a2 += w0*(float)v0[2] + w1*(float)v1[2] + w2*(float)v2[2] + w3*(float)v3[2]
            + w4*(float)v4[2] + w5*(float)v5[2] + w6*(float)v6[2] + w7*(float)v7[2];
        a3 += w0*(float)v0[3] + w1*(float)v1[3] + w2*(float)v2[3] + w3*(float)v3[3]
            + w4*(float)v4[3] + w5*(float)v5[3] + w6*(float)v6[3] + w7*(float)v7[3];
    }
    for (; i < end; i++) {
        int2 e = sedge[i];
        float w = __uint_as_float(e.y);
        bf16x4 v = base[(long)e.x * 64 + lane];
        a0 += w*(float)v[0]; a1 += w*(float)v[1];
        a2 += w*(float)v[2]; a3 += w*(float)v[3];
    }
    float4 bv = ((const float4*)bias)[lane];
    bf16x4 ov;
    ov[0] = (__bf16)fmaxf(a0 + bv.x, 0.f);
    ov[1] = (__bf16)fmaxf(a1 + bv.y, 0.f);
    ov[2] = (__bf16)fmaxf(a2 + bv.z, 0.f);
    ov[3] = (__bf16)fmaxf(a3 + bv.w, 0.f);
    ((bf16x4*)o)[(long)n * 64 + lane] = ov;
}

// ---------------- GEMM2 (MFMA): HMb = bf16(h @ [W_mu|W_lv]), h is NN x 256 ----------------
// BM=128, BN=128, BK=32. 4 waves in 2x2.
__global__ __launch_bounds__(256) void k_gemm2(const __bf16* __restrict__ h,
                                               const __bf16* __restrict__ Wp,
                                               __bf16* __restrict__ HMb) {
    __shared__ __bf16 As[128 * PAD];
    int tid = threadIdx.x;
    int wv = tid >> 6, lane = tid & 63;
    int quad = lane >> 4, l16 = lane & 15;
    int wr = (wv >> 1) * 64, wc = (wv & 1) * 64;
    long m0 = (long)blockIdx.x * 128;

    int srow = tid >> 1;            // 0..127
    int scol = (tid & 1) * 16;      // 0,16
    long grow = m0 + srow; if (grow > NN - 1) grow = NN - 1;

    f32x4 acc[4][4];
#pragma unroll
    for (int a = 0; a < 4; a++)
#pragma unroll
        for (int b = 0; b < 4; b++) acc[a][b] = (f32x4)0.f;

    const __bf16* rH = h + grow * 256;
    bf16x8 p0 = *(const bf16x8*)(rH + scol);
    bf16x8 p1 = *(const bf16x8*)(rH + scol + 8);

    for (int kc = 0; kc < 8; kc++) {
        *(bf16x8*)&As[srow * PAD + scol] = p0;
        *(bf16x8*)&As[srow * PAD + scol + 8] = p1;
        __syncthreads();
        if (kc < 7) {
            const __bf16* nxt = rH + (kc + 1) * 32;
            p0 = *(const bf16x8*)(nxt + scol);
            p1 = *(const bf16x8*)(nxt + scol + 8);
        }
        bf16x8 bfr[4];
#pragma unroll
        for (int nt = 0; nt < 4; nt++) {
            int ntg = (wc >> 4) + nt;
            bfr[nt] = *(const bf16x8*)(Wp + (((long)ntg * 8 + kc) * 64 + lane) * 8);
        }
#pragma unroll
        for (int mt = 0; mt < 4; mt++) {
            bf16x8 af = *(const bf16x8*)&As[(wr + mt * 16 + l16) * PAD + quad * 8];
#pragma unroll
            for (int nt = 0; nt < 4; nt++)
                acc[mt][nt] = __builtin_amdgcn_mfma_f32_16x16x32_bf16(af, bfr[nt], acc[mt][nt], 0, 0, 0);
        }
        __syncthreads();
    }
#pragma unroll
    for (int mt = 0; mt < 4; mt++)
#pragma unroll
        for (int r = 0; r < 4; r++) {
            long gr = m0 + wr + mt * 16 + quad * 4 + r;
            if (gr < NN) {
#pragma unroll
                for (int nt = 0; nt < 4; nt++)
                    HMb[gr * 128 + wc + nt * 16 + l16] = (__bf16)acc[mt][nt][r];
            }
        }
}

// ---------------- SpMM2 + bias: out = [adj@HM + b_mu ; adj@HL + b_lv] ----------------
__global__ __launch_bounds__(256) void k_spmm2(const __bf16* __restrict__ HMb,
                                               const int2* __restrict__ sedge,
                                               const int* __restrict__ row_ptr,
                                               const int* __restrict__ deg,
                                               const float* __restrict__ bmu,
                                               const float* __restrict__ blv,
                                               float* __restrict__ out) {
    int wave = threadIdx.x >> 6, lane = threadIdx.x & 63;
    int n = blockIdx.x * 4 + wave;
    if (n >= NN) return;
    int i = row_ptr[n];
    int end = i + deg[n];
    float a0 = 0.f, a1 = 0.f;
    const bf16x2* base = (const bf16x2*)HMb;  // row stride 64 bf16x2
    for (; i + 8 <= end; i += 8) {
        int2 e0 = sedge[i], e1 = sedge[i+1], e2 = sedge[i+2], e3 = sedge[i+3];
        int2 e4 = sedge[i+4], e5 = sedge[i+5], e6 = sedge[i+6], e7 = sedge[i+7];
        bf16x2 v0 = base[(long)e0.x * 64 + lane];
        bf16x2 v1 = base[(long)e1.x * 64 + lane];
        bf16x2 v2 = base[(long)e2.x * 64 + lane];
        bf16x2 v3 = base[(long)e3.x * 64 + lane];
        bf16x2 v4 = base[(long)e4.x * 64 + lane];
        bf16x2 v5 = base[(long)e5.x * 64 + lane];
        bf16x2 v6 = base[(long)e6.x * 64 + lane];
        bf16x2 v7 = base[(long)e7.x * 64 + lane];
        a0 += __uint_as_float(e0.y) * (float)v0[0] + __uint_as_float(e1.y) * (float)v1[0]
            + __uint_as_float(e2.y) * (float)v2[0] + __uint_as_float(e3.y) * (float)v3[0]
            + __uint_as_float(e4.y) * (float)v4[0] + __uint_as_float(e5.y) * (float)v5[0]
            + __uint_as_float(e6.y) * (float)v6[0] + __uint_as_float(e7.y) * (float)v7[0];
        a1 += __uint_as_float(e0.y) * (float)v0[1] + __uint_as_float(e1.y) * (float)v1[1]
            + __uint_as_float(e2.y) * (float)v2[1] + __uint_as_float(e3.y) * (float)v3[1]
            + __uint_as_float(e4.y) * (float)v4[1] + __uint_as_float(e5.y) * (float)v5[1]
            + __uint_as_float(e6.y) * (float)v6[1] + __uint_as_float(e7.y) * (float)v7[1];
    }
    for (; i < end; i++) {
        int2 e = sedge[i];
        float w = __uint_as_float(e.y);
        bf16x2 v = base[(long)e.x * 64 + lane];
        a0 += w * (float)v[0]; a1 += w * (float)v[1];
    }
    if (lane < 32) {  // cols 0..63 -> mu
        float2 b = ((const float2*)bmu)[lane];
        float2 o = {a0 + b.x, a1 + b.y};
        ((float2*)out)[(long)n * 32 + lane] = o;
    } else {          // cols 64..127 -> logvar
        float2 b = ((const float2*)blv)[lane - 32];
        float2 o = {a0 + b.x, a1 + b.y};
        ((float2*)(out + (long)NN * NL))[(long)n * 32 + (lane - 32)] = o;
    }
}

extern "C" void kernel_launch(void* const* d_in, const int* in_sizes, int n_in,
                              void* d_out, int out_size, void* d_ws, size_t ws_size,
                              hipStream_t stream) {
    const float* x   = (const float*)d_in[0];
    const int*   ei  = (const int*)d_in[1];
    const float* ew  = (const float*)d_in[2];
    const float* W1  = (const float*)d_in[3];
    const float* b1  = (const float*)d_in[4];
    const float* Wmu = (const float*)d_in[5];
    const float* bmu = (const float*)d_in[6];
    const float* Wlv = (const float*)d_in[7];
    const float* blv = (const float*)d_in[8];
    float* out = (float*)d_out;

    char* ws = (char*)d_ws;
    __bf16* XW     = (__bf16*)(ws);                  // NN*256 bf16 (51.2 MB)
    __bf16* h      = (__bf16*)(ws + 51200000);       // NN*256 bf16 (51.2 MB)
    __bf16* HMb    = (__bf16*)(ws + 102400000);      // NN*128 bf16 (25.6 MB)
    int2*  sedge   = (int2*) (ws + 128000000);       // NE * 8 B (25.6 MB)
    int*   deg     = (int*)  (ws + 153600000);       // NN
    int*   row_ptr = (int*)  (ws + 154000000);       // NN
    int*   bcur    = (int*)  (ws + 154400000);       // NBKT padded counters (16KB)
    int*   bstart  = (int*)  (ws + 154800000);       // NBKT+1
    __bf16* Wp1    = (__bf16*)(ws + 154900000);      // 131072 bf16
    __bf16* Wp2    = (__bf16*)(ws + 155200000);      // 32768 bf16

    // CSR-build staging aliases the h region (dead until k_spmm_h):
    int2* stage_sw = (int2*)(ws + 51200000);                          // 27.65 MB
    int*  stage_d  = (int*) (ws + 51200000 + (long)NBKT * CAP * 8);   // 13.8 MB

    const int* esrc = ei;
    const int* edst = ei + NE;

    // weight packing
    k_packW1<<<dim3(512), dim3(256), 0, stream>>>(W1, Wp1);
    k_packW2<<<dim3(128), dim3(256), 0, stream>>>(Wmu, Wlv, Wp2);

    // CSR build: bucket-partition -> bucket scan -> per-bucket deg/class-sorted scatter
    k_binit2<<<dim3(1), dim3(NBKT), 0, stream>>>(bcur);
    k_bucket0<<<dim3(NE / 1024), dim3(256), 0, stream>>>(esrc, edst, (const int*)ew,
                                                         bcur, stage_sw, stage_d);
    k_bscan<<<dim3(1), dim3(NBKT), 0, stream>>>(bcur, bstart);
    k_build<<<dim3(NBKT), dim3(512), 0, stream>>>(stage_sw, stage_d, bcur, bstart,
                                                  deg, row_ptr, sedge);

    // layer 1
    k_gemm1<<<dim3((NN + 63) / 64), dim3(256), 0, stream>>>(x, Wp1, XW);
    k_spmm_h<<<dim3((NN + 3) / 4), dim3(256), 0, stream>>>(XW, sedge, row_ptr, deg, b1, h);

    // layer 2
    k_gemm2<<<dim3((NN + 127) / 128), dim3(256), 0, stream>>>(h, Wp2, HMb);
    k_spmm2<<<dim3((NN + 3) / 4), dim3(256), 0, stream>>>(HMb, sedge, row_ptr, deg, bmu, blv, out);
}

// Round 4
// 812.291 us; speedup vs baseline: 1.2268x; 1.0374x over previous
//
#include <hip/hip_runtime.h>
#include <hip/hip_bf16.h>

#define NN 100000
#define NE 3200000
#define NF 512
#define NH 256
#define NL 64
#define PAD 40        // LDS row stride in bf16 elems (GEMMs)

#define NBKT 250      // dst-range buckets (250*400 = 100000 exact)
#define NPB 400       // nodes per bucket
#define CAP 13600     // staging capacity per bucket (mean 12800, sigma ~113)
#define NCLS 16       // src classes for gather phase-locality
#define DIVC 6250     // NN / NCLS
#define RPW 8         // rows per subgroup (one wave owns one subgroup)
#define SGB 50        // subgroups per bucket (NPB / RPW)
#define NSG 12500     // total subgroups (NN / RPW)

typedef __bf16 bf16x8 __attribute__((ext_vector_type(8)));
typedef __bf16 bf16x4 __attribute__((ext_vector_type(4)));
typedef __bf16 bf16x2 __attribute__((ext_vector_type(2)));
typedef float  f32x4  __attribute__((ext_vector_type(4)));
typedef float  f32x2  __attribute__((ext_vector_type(2)));

// ---------------- CSR build (bucket-local, (subgroup,class)-run layout) ----------------
// bcur is padded: counter for bucket b lives at bcur[b*16] (one 64B line each).
__global__ void k_binit2(int* __restrict__ bcur) {
    int t = threadIdx.x;          // 256 threads
    if (t < NBKT) bcur[t * 16] = t * CAP;
}

// Phase 1: partition edges into 250 dst-range buckets (fixed-capacity slots).
// Per-block LDS counting + one global reservation atomic per bucket per block.
// stage_d packs dst (20 bits) | src-class << 20.
__global__ __launch_bounds__(256) void k_bucket0(const int* __restrict__ src,
                                                 const int* __restrict__ dst,
                                                 const int* __restrict__ wbits,
                                                 int* __restrict__ bcur,
                                                 int2* __restrict__ stage_sw,
                                                 int* __restrict__ stage_d) {
    __shared__ int cnt[NBKT];
    __shared__ int base[NBKT];
    int tid = threadIdx.x;
    if (tid < NBKT) cnt[tid] = 0;
    __syncthreads();
    int e0 = blockIdx.x * 1024;   // NE % 1024 == 0, no bounds check
    int ss[4], ww[4], dd[4], lr[4], bb[4];
#pragma unroll
    for (int k = 0; k < 4; k++) {
        int e = e0 + k * 256 + tid;
        int d = dst[e];
        int s = src[e];
        ss[k] = s;
        ww[k] = wbits[e];
        int cls = (int)((unsigned)s / DIVC);
        dd[k] = d | (cls << 20);
        bb[k] = (int)((unsigned)d / NPB);
        lr[k] = atomicAdd(&cnt[bb[k]], 1);
    }
    __syncthreads();
    if (tid < NBKT) base[tid] = atomicAdd(&bcur[tid * 16], cnt[tid]);
    __syncthreads();
#pragma unroll
    for (int k = 0; k < 4; k++) {
        int pos = base[bb[k]] + lr[k];
        stage_sw[pos] = make_int2(ss[k], ww[k]);
        stage_d[pos] = dd[k];
    }
}

// Exclusive scan of bucket fills -> bstart; also writes the run_off sentinel.
__global__ void k_bscan(const int* __restrict__ bcur, int* __restrict__ bstart,
                        int* __restrict__ run_off) {
    __shared__ int s[256];
    int t = threadIdx.x;          // 256 threads
    int v = (t < NBKT) ? (bcur[t * 16] - t * CAP) : 0;
    s[t] = v;
    __syncthreads();
    for (int off = 1; off < 256; off <<= 1) {
        int a = (t >= off) ? s[t - off] : 0;
        __syncthreads();
        s[t] += a;
        __syncthreads();
    }
    if (t < NBKT) bstart[t] = s[t] - v;  // exclusive
    if (t == 0) run_off[NSG * NCLS] = NE;
}

// Phase 2: one WG per bucket. Histogram [subgroup][class] -> contiguous
// (subgroup, class) runs in sedge; run starts exported to run_off.
// sedge.x packs src (20 bits) | dst_local(3 bits) << 20.
__global__ __launch_bounds__(512) void k_build(const int2* __restrict__ stage_sw,
                                               const int* __restrict__ stage_d,
                                               const int* __restrict__ bcur,
                                               const int* __restrict__ bstart,
                                               int* __restrict__ run_off,
                                               int2* __restrict__ sedge) {
    __shared__ int hist[SGB * NCLS];    // counts -> absolute cursors
    __shared__ int sgtot[SGB];
    __shared__ int sgoff[SGB];
    int b = blockIdx.x;
    int t = threadIdx.x;
    int n0 = b * NPB;
    int s0 = b * CAP;
    int fill = bcur[b * 16] - s0;

    for (int i = t; i < SGB * NCLS; i += 512) hist[i] = 0;
    __syncthreads();
    for (int i = t; i < fill; i += 512) {
        int v = stage_d[s0 + i];
        int d = v & 0xFFFFF, c = v >> 20;
        atomicAdd(&hist[((d - n0) >> 3) * NCLS + c], 1);
    }
    __syncthreads();
    if (t < SGB) {
        int sum = 0;
#pragma unroll
        for (int c = 0; c < NCLS; c++) sum += hist[t * NCLS + c];
        sgtot[t] = sum;
    }
    __syncthreads();
    if (t == 0) {
        int a = 0;
        for (int sgi = 0; sgi < SGB; sgi++) { sgoff[sgi] = a; a += sgtot[sgi]; }
    }
    __syncthreads();
    if (t < SGB) {
        int a = bstart[b] + sgoff[t];
#pragma unroll
        for (int c = 0; c < NCLS; c++) {
            int tmp = hist[t * NCLS + c];
            hist[t * NCLS + c] = a;
            run_off[(long)(b * SGB + t) * NCLS + c] = a;
            a += tmp;
        }
    }
    __syncthreads();
    for (int i = t; i < fill; i += 512) {
        int v = stage_d[s0 + i];
        int d = v & 0xFFFFF, c = v >> 20;
        int pos = atomicAdd(&hist[((d - n0) >> 3) * NCLS + c], 1);
        int2 sw = stage_sw[s0 + i];
        sedge[pos] = make_int2(sw.x | ((d & 7) << 20), sw.y);
    }
}

// ---------------- weight packing into MFMA B-fragment order ----------------
__global__ void k_packW1(const float* __restrict__ W, __bf16* __restrict__ P) {
    int i = blockIdx.x * 256 + threadIdx.x;       // 131072 = 16nt * 16kc * 64 * 8
    int j = i & 7, l = (i >> 3) & 63, kc = (i >> 9) & 15, nt = i >> 13;
    int k = kc * 32 + (l >> 4) * 8 + j;
    int n = nt * 16 + (l & 15);
    P[i] = (__bf16)W[k * NH + n];
}

__global__ void k_packW2(const float* __restrict__ Wmu, const float* __restrict__ Wlv,
                         __bf16* __restrict__ P) {
    int i = blockIdx.x * 256 + threadIdx.x;       // 32768 = 8nt * 8kc * 64 * 8
    int j = i & 7, l = (i >> 3) & 63, kc = (i >> 9) & 7, nt = i >> 12;
    int k = kc * 32 + (l >> 4) * 8 + j;
    int n = nt * 16 + (l & 15);
    float v = (n < NL) ? Wmu[k * NL + n] : Wlv[k * NL + (n - NL)];
    P[i] = (__bf16)v;
}

// ---------------- GEMM1 (MFMA): XW interleaved table NN x 256 ----------------
__global__ __launch_bounds__(256) void k_gemm1(const float* __restrict__ x,
                                               const __bf16* __restrict__ Wp,
                                               __bf16* __restrict__ T) {
    __shared__ __bf16 As[64 * PAD];
    int tid = threadIdx.x;
    int wv = tid >> 6, lane = tid & 63;
    int quad = lane >> 4, l16 = lane & 15;
    long m0 = (long)blockIdx.x * 64;

    int srow = tid >> 2;            // 0..63
    int scol = (tid & 3) * 8;       // 0,8,16,24
    long grow = m0 + srow; if (grow > NN - 1) grow = NN - 1;
    const float* xrow = x + grow * NF;

    f32x4 acc[4][4];
#pragma unroll
    for (int a = 0; a < 4; a++)
#pragma unroll
        for (int b = 0; b < 4; b++) acc[a][b] = (f32x4)0.f;

    float4 p0 = *(const float4*)(xrow + scol);
    float4 p1 = *(const float4*)(xrow + scol + 4);

    for (int kc = 0; kc < 16; kc++) {
        union { bf16x8 v; __bf16 e[8]; } u;
        u.e[0] = (__bf16)p0.x; u.e[1] = (__bf16)p0.y;
        u.e[2] = (__bf16)p0.z; u.e[3] = (__bf16)p0.w;
        u.e[4] = (__bf16)p1.x; u.e[5] = (__bf16)p1.y;
        u.e[6] = (__bf16)p1.z; u.e[7] = (__bf16)p1.w;
        *(bf16x8*)&As[srow * PAD + scol] = u.v;
        __syncthreads();
        if (kc < 15) {
            p0 = *(const float4*)(xrow + (kc + 1) * 32 + scol);
            p1 = *(const float4*)(xrow + (kc + 1) * 32 + scol + 4);
        }
        bf16x8 bfr[4];
#pragma unroll
        for (int nt = 0; nt < 4; nt++)
            bfr[nt] = *(const bf16x8*)(Wp + (((long)(wv * 4 + nt) * 16 + kc) * 64 + lane) * 8);
#pragma unroll
        for (int mt = 0; mt < 4; mt++) {
            bf16x8 af = *(const bf16x8*)&As[(mt * 16 + l16) * PAD + quad * 8];
#pragma unroll
            for (int nt = 0; nt < 4; nt++)
                acc[mt][nt] = __builtin_amdgcn_mfma_f32_16x16x32_bf16(af, bfr[nt], acc[mt][nt], 0, 0, 0);
        }
        __syncthreads();
    }
#pragma unroll
    for (int mt = 0; mt < 4; mt++)
#pragma unroll
        for (int r = 0; r < 4; r++) {
            long gr = m0 + mt * 16 + quad * 4 + r;
            if (gr < NN) {
#pragma unroll
                for (int nt = 0; nt < 4; nt++)
                    T[gr * 256 + wv * 64 + nt * 16 + l16] = (__bf16)acc[mt][nt][r];
            }
        }
}

// ---------------- SpMM layer 1: class-phased, LDS accumulators ----------------
// Wave owns subgroup sg (rows sg*8..sg*8+7), accum 8x256 f32 in LDS.
// Edges arrive in contiguous (sg, class) runs -> all resident waves gather
// from the same 3.2MB class slice of T at the same time (L2-resident).
#define RMW4(EV, VV) { float w = __uint_as_float(EV.y); \
    f32x4* a = &A[((EV).x >> 20) * 64 + lane]; f32x4 tt = *a; \
    tt[0] += w * (float)VV[0]; tt[1] += w * (float)VV[1]; \
    tt[2] += w * (float)VV[2]; tt[3] += w * (float)VV[3]; *a = tt; }

__global__ __launch_bounds__(256) void k_spmm_h(const __bf16* __restrict__ T,
                                                const int2* __restrict__ sedge,
                                                const int* __restrict__ roff,
                                                const float* __restrict__ bias,
                                                __bf16* __restrict__ o) {
    __shared__ f32x4 acc[4][RPW][64];   // 32 KB
    int wv = __builtin_amdgcn_readfirstlane(threadIdx.x >> 6);
    int lane = threadIdx.x & 63;
    int sg = blockIdx.x * 4 + wv;       // NSG = 12500 = 3125*4 exact
    f32x4* A = &acc[wv][0][0];
    for (int i = lane; i < RPW * 64; i += 64) A[i] = (f32x4)0.f;
    const bf16x4* base = (const bf16x4*)T;
    for (int c = 0; c < NCLS; c++) {
        int i = roff[sg * NCLS + c];
        int e = roff[sg * NCLS + c + 1];
        for (; i + 8 <= e; i += 8) {
            int2 e0 = sedge[i], e1 = sedge[i+1], e2 = sedge[i+2], e3 = sedge[i+3];
            int2 e4 = sedge[i+4], e5 = sedge[i+5], e6 = sedge[i+6], e7 = sedge[i+7];
            bf16x4 v0 = base[(long)(e0.x & 0xFFFFF) * 64 + lane];
            bf16x4 v1 = base[(long)(e1.x & 0xFFFFF) * 64 + lane];
            bf16x4 v2 = base[(long)(e2.x & 0xFFFFF) * 64 + lane];
            bf16x4 v3 = base[(long)(e3.x & 0xFFFFF) * 64 + lane];
            bf16x4 v4 = base[(long)(e4.x & 0xFFFFF) * 64 + lane];
            bf16x4 v5 = base[(long)(e5.x & 0xFFFFF) * 64 + lane];
            bf16x4 v6 = base[(long)(e6.x & 0xFFFFF) * 64 + lane];
            bf16x4 v7 = base[(long)(e7.x & 0xFFFFF) * 64 + lane];
            RMW4(e0, v0) RMW4(e1, v1) RMW4(e2, v2) RMW4(e3, v3)
            RMW4(e4, v4) RMW4(e5, v5) RMW4(e6, v6) RMW4(e7, v7)
        }
        for (; i + 4 <= e; i += 4) {
            int2 e0 = sedge[i], e1 = sedge[i+1], e2 = sedge[i+2], e3 = sedge[i+3];
            bf16x4 v0 = base[(long)(e0.x & 0xFFFFF) * 64 + lane];
            bf16x4 v1 = base[(long)(e1.x & 0xFFFFF) * 64 + lane];
            bf16x4 v2 = base[(long)(e2.x & 0xFFFFF) * 64 + lane];
            bf16x4 v3 = base[(long)(e3.x & 0xFFFFF) * 64 + lane];
            RMW4(e0, v0) RMW4(e1, v1) RMW4(e2, v2) RMW4(e3, v3)
        }
        for (; i < e; i++) {
            int2 e0 = sedge[i];
            bf16x4 v0 = base[(long)(e0.x & 0xFFFFF) * 64 + lane];
            RMW4(e0, v0)
        }
    }
    float4 bv = ((const float4*)bias)[lane];
    long n0 = (long)sg * RPW;
#pragma unroll
    for (int r = 0; r < RPW; r++) {
        f32x4 t = A[r * 64 + lane];
        bf16x4 ov;
        ov[0] = (__bf16)fmaxf(t[0] + bv.x, 0.f);
        ov[1] = (__bf16)fmaxf(t[1] + bv.y, 0.f);
        ov[2] = (__bf16)fmaxf(t[2] + bv.z, 0.f);
        ov[3] = (__bf16)fmaxf(t[3] + bv.w, 0.f);
        ((bf16x4*)o)[(n0 + r) * 64 + lane] = ov;
    }
}

// ---------------- GEMM2 (MFMA): HMb = bf16(h @ [W_mu|W_lv]), h is NN x 256 ----------------
__global__ __launch_bounds__(256) void k_gemm2(const __bf16* __restrict__ h,
                                               const __bf16* __restrict__ Wp,
                                               __bf16* __restrict__ HMb) {
    __shared__ __bf16 As[128 * PAD];
    int tid = threadIdx.x;
    int wv = tid >> 6, lane = tid & 63;
    int quad = lane >> 4, l16 = lane & 15;
    int wr = (wv >> 1) * 64, wc = (wv & 1) * 64;
    long m0 = (long)blockIdx.x * 128;

    int srow = tid >> 1;            // 0..127
    int scol = (tid & 1) * 16;      // 0,16
    long grow = m0 + srow; if (grow > NN - 1) grow = NN - 1;

    f32x4 acc[4][4];
#pragma unroll
    for (int a = 0; a < 4; a++)
#pragma unroll
        for (int b = 0; b < 4; b++) acc[a][b] = (f32x4)0.f;

    const __bf16* rH = h + grow * 256;
    bf16x8 p0 = *(const bf16x8*)(rH + scol);
    bf16x8 p1 = *(const bf16x8*)(rH + scol + 8);

    for (int kc = 0; kc < 8; kc++) {
        *(bf16x8*)&As[srow * PAD + scol] = p0;
        *(bf16x8*)&As[srow * PAD + scol + 8] = p1;
        __syncthreads();
        if (kc < 7) {
            const __bf16* nxt = rH + (kc + 1) * 32;
            p0 = *(const bf16x8*)(nxt + scol);
            p1 = *(const bf16x8*)(nxt + scol + 8);
        }
        bf16x8 bfr[4];
#pragma unroll
        for (int nt = 0; nt < 4; nt++) {
            int ntg = (wc >> 4) + nt;
            bfr[nt] = *(const bf16x8*)(Wp + (((long)ntg * 8 + kc) * 64 + lane) * 8);
        }
#pragma unroll
        for (int mt = 0; mt < 4; mt++) {
            bf16x8 af = *(const bf16x8*)&As[(wr + mt * 16 + l16) * PAD + quad * 8];
#pragma unroll
            for (int nt = 0; nt < 4; nt++)
                acc[mt][nt] = __builtin_amdgcn_mfma_f32_16x16x32_bf16(af, bfr[nt], acc[mt][nt], 0, 0, 0);
        }
        __syncthreads();
    }
#pragma unroll
    for (int mt = 0; mt < 4; mt++)
#pragma unroll
        for (int r = 0; r < 4; r++) {
            long gr = m0 + wr + mt * 16 + quad * 4 + r;
            if (gr < NN) {
#pragma unroll
                for (int nt = 0; nt < 4; nt++)
                    HMb[gr * 128 + wc + nt * 16 + l16] = (__bf16)acc[mt][nt][r];
            }
        }
}

// ---------------- SpMM layer 2: class-phased, LDS accumulators ----------------
#define RMW2(EV, VV) { float w = __uint_as_float(EV.y); \
    f32x2* a = &A[((EV).x >> 20) * 64 + lane]; f32x2 tt = *a; \
    tt[0] += w * (float)VV[0]; tt[1] += w * (float)VV[1]; *a = tt; }

__global__ __launch_bounds__(256) void k_spmm2(const __bf16* __restrict__ HMb,
                                               const int2* __restrict__ sedge,
                                               const int* __restrict__ roff,
                                               const float* __restrict__ bmu,
                                               const float* __restrict__ blv,
                                               float* __restrict__ out) {
    __shared__ f32x2 acc[4][RPW][64];   // 16 KB
    int wv = __builtin_amdgcn_readfirstlane(threadIdx.x >> 6);
    int lane = threadIdx.x & 63;
    int sg = blockIdx.x * 4 + wv;
    f32x2* A = &acc[wv][0][0];
    for (int i = lane; i < RPW * 64; i += 64) A[i] = (f32x2)0.f;
    const bf16x2* base = (const bf16x2*)HMb;
    for (int c = 0; c < NCLS; c++) {
        int i = roff[sg * NCLS + c];
        int e = roff[sg * NCLS + c + 1];
        for (; i + 8 <= e; i += 8) {
            int2 e0 = sedge[i], e1 = sedge[i+1], e2 = sedge[i+2], e3 = sedge[i+3];
            int2 e4 = sedge[i+4], e5 = sedge[i+5], e6 = sedge[i+6], e7 = sedge[i+7];
            bf16x2 v0 = base[(long)(e0.x & 0xFFFFF) * 64 + lane];
            bf16x2 v1 = base[(long)(e1.x & 0xFFFFF) * 64 + lane];
            bf16x2 v2 = base[(long)(e2.x & 0xFFFFF) * 64 + lane];
            bf16x2 v3 = base[(long)(e3.x & 0xFFFFF) * 64 + lane];
            bf16x2 v4 = base[(long)(e4.x & 0xFFFFF) * 64 + lane];
            bf16x2 v5 = base[(long)(e5.x & 0xFFFFF) * 64 + lane];
            bf16x2 v6 = base[(long)(e6.x & 0xFFFFF) * 64 + lane];
            bf16x2 v7 = base[(long)(e7.x & 0xFFFFF) * 64 + lane];
            RMW2(e0, v0) RMW2(e1, v1) RMW2(e2, v2) RMW2(e3, v3)
            RMW2(e4, v4) RMW2(e5, v5) RMW2(e6, v6) RMW2(e7, v7)
        }
        for (; i + 4 <= e; i += 4) {
            int2 e0 = sedge[i], e1 = sedge[i+1], e2 = sedge[i+2], e3 = sedge[i+3];
            bf16x2 v0 = base[(long)(e0.x & 0xFFFFF) * 64 + lane];
            bf16x2 v1 = base[(long)(e1.x & 0xFFFFF) * 64 + lane];
            bf16x2 v2 = base[(long)(e2.x & 0xFFFFF) * 64 + lane];
            bf16x2 v3 = base[(long)(e3.x & 0xFFFFF) * 64 + lane];
            RMW2(e0, v0) RMW2(e1, v1) RMW2(e2, v2) RMW2(e3, v3)
        }
        for (; i < e; i++) {
            int2 e0 = sedge[i];
            bf16x2 v0 = base[(long)(e0.x & 0xFFFFF) * 64 + lane];
            RMW2(e0, v0)
        }
    }
    long n0 = (long)sg * RPW;
#pragma unroll
    for (int r = 0; r < RPW; r++) {
        f32x2 t = A[r * 64 + lane];
        float2 o2;
        if (lane < 32) {  // cols 0..63 -> mu
            float2 b = ((const float2*)bmu)[lane];
            o2.x = t[0] + b.x; o2.y = t[1] + b.y;
            ((float2*)out)[(n0 + r) * 32 + lane] = o2;
        } else {          // cols 64..127 -> logvar
            float2 b = ((const float2*)blv)[lane - 32];
            o2.x = t[0] + b.x; o2.y = t[1] + b.y;
            ((float2*)(out + (long)NN * NL))[(n0 + r) * 32 + (lane - 32)] = o2;
        }
    }
}

extern "C" void kernel_launch(void* const* d_in, const int* in_sizes, int n_in,
                              void* d_out, int out_size, void* d_ws, size_t ws_size,
                              hipStream_t stream) {
    const float* x   = (const float*)d_in[0];
    const int*   ei  = (const int*)d_in[1];
    const float* ew  = (const float*)d_in[2];
    const float* W1  = (const float*)d_in[3];
    const float* b1  = (const float*)d_in[4];
    const float* Wmu = (const float*)d_in[5];
    const float* bmu = (const float*)d_in[6];
    const float* Wlv = (const float*)d_in[7];
    const float* blv = (const float*)d_in[8];
    float* out = (float*)d_out;

    char* ws = (char*)d_ws;
    __bf16* XW     = (__bf16*)(ws);                  // NN*256 bf16 (51.2 MB)
    __bf16* h      = (__bf16*)(ws + 51200000);       // NN*256 bf16 (51.2 MB)
    __bf16* HMb    = (__bf16*)(ws + 102400000);      // NN*128 bf16 (25.6 MB)
    int2*  sedge   = (int2*) (ws + 128000000);       // NE * 8 B (25.6 MB)
    int*   run_off = (int*)  (ws + 153600000);       // NSG*16+1 ints (800 KB)
    int*   bcur    = (int*)  (ws + 154450000);       // NBKT padded counters (16 KB)
    int*   bstart  = (int*)  (ws + 154800000);       // NBKT
    __bf16* Wp1    = (__bf16*)(ws + 154900000);      // 131072 bf16
    __bf16* Wp2    = (__bf16*)(ws + 155200000);      // 32768 bf16

    // CSR-build staging aliases the h region (dead until k_spmm_h):
    int2* stage_sw = (int2*)(ws + 51200000);                          // 27.2 MB
    int*  stage_d  = (int*) (ws + 78400000);                          // 13.6 MB

    const int* esrc = ei;
    const int* edst = ei + NE;

    // weight packing
    k_packW1<<<dim3(512), dim3(256), 0, stream>>>(W1, Wp1);
    k_packW2<<<dim3(128), dim3(256), 0, stream>>>(Wmu, Wlv, Wp2);

    // CSR build: bucket-partition -> bucket scan -> (subgroup,class)-run layout
    k_binit2<<<dim3(1), dim3(256), 0, stream>>>(bcur);
    k_bucket0<<<dim3(NE / 1024), dim3(256), 0, stream>>>(esrc, edst, (const int*)ew,
                                                         bcur, stage_sw, stage_d);
    k_bscan<<<dim3(1), dim3(256), 0, stream>>>(bcur, bstart, run_off);
    k_build<<<dim3(NBKT), dim3(512), 0, stream>>>(stage_sw, stage_d, bcur, bstart,
                                                  run_off, sedge);

    // layer 1
    k_gemm1<<<dim3((NN + 63) / 64), dim3(256), 0, stream>>>(x, Wp1, XW);
    k_spmm_h<<<dim3(NSG / 4), dim3(256), 0, stream>>>(XW, sedge, run_off, b1, h);

    // layer 2
    k_gemm2<<<dim3((NN + 127) / 128), dim3(256), 0, stream>>>(h, Wp2, HMb);
    k_spmm2<<<dim3(NSG / 4), dim3(256), 0, stream>>>(HMb, sedge, run_off, bmu, blv, out);
}